// Round 8
// baseline (71.600 us; speedup 1.0000x reference)
//
#include <hip/hip_runtime.h>

static constexpr int    N      = 2048;
static constexpr int    NBLK   = 256;
static constexpr int    NTHR   = 1024;
static constexpr int    RPB    = 8;     // rows (or cols) per block
static constexpr double D_MASS = 0.9;
static constexpr double D_TOL  = 0.01;
static constexpr int    NITER  = 50;

typedef _Float16 half4_t __attribute__((ext_vector_type(4)));
typedef _Float16 half2_t __attribute__((ext_vector_type(2)));

struct Ws {
    unsigned cntP, cntV, cntE, _pad;     // counters for fallback only (zeroed by K1)
    double a_sum, b_sum;
    double bandSum[NBLK];                // sum K0 over band
    double s2Band[NBLK];                 // sum K0^2 over band
    double rowSum[N];
    double dotParts[NBLK], errAParts[NBLK], errBParts[NBLK];
    double errParts[NBLK];               // fallback err-iter partials
    float  U[N], row_prev[N], V[N], col_prev[N], Vp[N];
    float  partialT[(size_t)N * NBLK];   // [col][srcblk], 2 MB
    float  partialG[(size_t)N * NBLK];   // U * K0^2
    float  partialH[(size_t)N * NBLK];   // U^2 * K0^2
};

// deterministic all-thread block reduction (1024 threads, 16 waves)
__device__ __forceinline__ double block_reduce(double v, double* s16) {
    for (int off = 32; off; off >>= 1) v += __shfl_xor(v, off, 64);
    const int wave = threadIdx.x >> 6, lane = threadIdx.x & 63;
    __syncthreads();
    if (lane == 0) s16[wave] = v;
    __syncthreads();
    double s = 0.0;
    #pragma unroll
    for (int w = 0; w < 16; ++w) s += s16[w];
    return s;
}

// counter-based exchange (fallback only; proven in round 5)
__device__ __forceinline__ void arrive(unsigned* cnt) {
    __syncthreads();
    if (threadIdx.x == 0)
        __hip_atomic_fetch_add(cnt, 1u, __ATOMIC_RELEASE, __HIP_MEMORY_SCOPE_AGENT);
}
__device__ __forceinline__ void wait_cnt(unsigned* cnt, unsigned target) {
    if (threadIdx.x == 0) {
        while (__hip_atomic_load(cnt, __ATOMIC_RELAXED, __HIP_MEMORY_SCOPE_AGENT) < target)
            __builtin_amdgcn_s_sleep(2);
        __builtin_amdgcn_fence(__ATOMIC_ACQUIRE, "agent");
    }
    __syncthreads();
}

// ---- K1: row sums + band sums of K0 and K0^2, a/b sums, zero counters ----
__global__ void __launch_bounds__(NTHR)
k1_sums(const float* __restrict__ C, const float* __restrict__ a,
        const float* __restrict__ b, Ws* __restrict__ ws)
{
    __shared__ double s16[16];
    const int tid = threadIdx.x, bid = blockIdx.x, lane = tid & 63;
    const int r0 = bid * RPB, rloc = tid >> 7, cgrp = tid & 127;

    if (bid == 0 && tid == 0) { ws->cntP = 0u; ws->cntV = 0u; ws->cntE = 0u; }
    if (bid == 0) {
        double t = block_reduce((double)a[tid] + (double)a[tid + 1024], s16);
        if (tid == 0) ws->a_sum = t;
    } else if (bid == 1) {
        double t = block_reduce((double)b[tid] + (double)b[tid + 1024], s16);
        if (tid == 0) ws->b_sum = t;
    }

    const int i = r0 + rloc;
    const float4* c4 = (const float4*)(C + (size_t)i * N);
    double s = 0.0, s2 = 0.0;
    #pragma unroll 4
    for (int j4 = cgrp; j4 < N / 4; j4 += 128) {
        float4 c = c4[j4];
        const double ex = (double)expf(-10.0f * c.x);
        const double ey = (double)expf(-10.0f * c.y);
        const double ez = (double)expf(-10.0f * c.z);
        const double ew = (double)expf(-10.0f * c.w);
        s  += ex + ey + ez + ew;
        s2 += ex * ex + ey * ey + ez * ez + ew * ew;
    }
    for (int off = 32; off; off >>= 1) s += __shfl_xor(s, off, 64);
    __syncthreads();                     // s16 free (block_reduce readers done)
    if (lane == 0) s16[tid >> 6] = s;    // 2 waves per row
    __syncthreads();
    if (tid < RPB) ws->rowSum[r0 + tid] = s16[2 * tid] + s16[2 * tid + 1];
    if (tid == 0) {
        double bs = 0.0;
        #pragma unroll
        for (int w = 0; w < 16; ++w) bs += s16[w];
        ws->bandSum[bid] = bs;
    }
    const double bs2 = block_reduce(s2, s16);
    if (tid == 0) ws->s2Band[bid] = bs2;
}

// ---- K2: iter-0 row scaling (U), column partials T/G/H -> [col][srcblk] ----
__global__ void __launch_bounds__(NTHR)
k2_rowscale_colpart(const float* __restrict__ C, const float* __restrict__ a,
                    Ws* __restrict__ ws)
{
    __shared__ double s16[16];
    __shared__ double sU[RPB];
    const int tid = threadIdx.x, bid = blockIdx.x;
    const int r0 = bid * RPB;

    const double k0sum = block_reduce((tid < NBLK) ? ws->bandSum[tid] : 0.0, s16);
    const double W0 = D_MASS / k0sum;

    if (tid < RPB) {
        const int i = r0 + tid;
        double r = ((double)a[i] / ws->a_sum) / (W0 * ws->rowSum[i]);
        if (r > 1.0) r = 1.0;
        sU[tid] = r;
        ws->U[i] = (float)r;
        ws->row_prev[i] = (float)r;
    }
    __syncthreads();

    double ub[RPB], ub2[RPB];
    #pragma unroll
    for (int r = 0; r < RPB; ++r) { ub[r] = sU[r]; ub2[r] = sU[r] * sU[r]; }
    const int j0 = 2 * tid;
    double ax = 0.0, ay = 0.0, gx = 0.0, gy = 0.0, hx = 0.0, hy = 0.0;
    #pragma unroll
    for (int r = 0; r < RPB; ++r) {
        const float2 c = *(const float2*)(C + (size_t)(r0 + r) * N + j0);
        const double ex = (double)expf(-10.0f * c.x);
        const double ey = (double)expf(-10.0f * c.y);
        ax += ex * ub[r];            ay += ey * ub[r];
        gx += ex * ex * ub[r];       gy += ey * ey * ub[r];
        hx += ex * ex * ub2[r];      hy += ey * ey * ub2[r];
    }
    ws->partialT[(size_t)j0 * NBLK + bid]       = (float)ax;
    ws->partialT[(size_t)(j0 + 1) * NBLK + bid] = (float)ay;
    ws->partialG[(size_t)j0 * NBLK + bid]       = (float)gx;
    ws->partialG[(size_t)(j0 + 1) * NBLK + bid] = (float)gy;
    ws->partialH[(size_t)j0 * NBLK + bid]       = (float)hx;
    ws->partialH[(size_t)(j0 + 1) * NBLK + bid] = (float)hy;
}

// ---- K3: reduce T/G/H, col scaling, V, dot + err-component partials ----
__global__ void __launch_bounds__(256)
k3_colscale(const float* __restrict__ b, Ws* __restrict__ ws)
{
    __shared__ double s4[4];
    __shared__ double sT[RPB], sG[RPB], sH[RPB];
    __shared__ double sD[RPB], sA[RPB], sB[RPB];
    const int tid = threadIdx.x, bid = blockIdx.x;

    double v = (double)ws->bandSum[tid];     // 256 values, one per thread
    for (int off = 32; off; off >>= 1) v += __shfl_xor(v, off, 64);
    if ((tid & 63) == 0) s4[tid >> 6] = v;
    __syncthreads();
    const double W0 = D_MASS / (s4[0] + s4[1] + s4[2] + s4[3]);

    const int jj = tid >> 5, p = tid & 31;   // 32 threads per column
    const int j = bid * RPB + jj;
    double t = 0.0, g = 0.0, h = 0.0;
    #pragma unroll
    for (int q = 0; q < 8; ++q) {
        const size_t idx = (size_t)j * NBLK + p + 32 * q;
        t += (double)ws->partialT[idx];
        g += (double)ws->partialG[idx];
        h += (double)ws->partialH[idx];
    }
    #pragma unroll
    for (int off = 16; off; off >>= 1) {
        t += __shfl_xor(t, off, 64);
        g += __shfl_xor(g, off, 64);
        h += __shfl_xor(h, off, 64);
    }
    if (p == 0) { sT[jj] = t; sG[jj] = g; sH[jj] = h; }
    __syncthreads();

    if (tid < RPB) {
        const int jc = bid * RPB + tid;
        const double Tj = sT[tid];
        double cf = ((double)b[jc] / ws->b_sum) / (W0 * Tj);   // Vq = 1
        if (cf > 1.0) cf = 1.0;
        ws->V[jc] = (float)cf;
        ws->col_prev[jc] = (float)cf;
        sD[tid] = Tj * cf;
        sA[tid] = sG[tid] * cf;          // V_j * G_j
        sB[tid] = sH[tid] * cf * cf;     // V_j^2 * H_j
    }
    __syncthreads();
    if (tid == 0) {
        double d = 0.0, ea = 0.0, eb = 0.0;
        #pragma unroll
        for (int q = 0; q < RPB; ++q) { d += sD[q]; ea += sA[q]; eb += sB[q]; }
        ws->dotParts[bid] = d;
        ws->errAParts[bid] = ea;
        ws->errBParts[bid] = eb;
    }
}

// ---- K45: closed-form done decision; fast path = single output write.
//      Fallback (never taken on converging data): iterate with counters. ----
__global__ void __launch_bounds__(NTHR, 1)
k45_out_iters(const float* __restrict__ C, const float* __restrict__ a,
              const float* __restrict__ b, float* __restrict__ K,
              Ws* __restrict__ ws)
{
    __shared__ _Float16 band[RPB][N];        // used by fallback only (32 KB)
    __shared__ double s16[16];
    __shared__ double sU[RPB], sUp[RPB], sRowPrev[RPB];
    __shared__ double sVown[RPB], sColPrev[RPB], sAn[RPB], sBn[RPB], sDot[RPB];

    const int tid = threadIdx.x, bid = blockIdx.x, lane = tid & 63;
    const int r0 = bid * RPB, rloc = tid >> 7, cgrp = tid & 127;

    // redundant scalar reduces (bitwise-identical in every block)
    const double k0sum = block_reduce((tid < NBLK) ? ws->bandSum[tid]  : 0.0, s16);
    const double s2tot = block_reduce((tid < NBLK) ? ws->s2Band[tid]   : 0.0, s16);
    const double sd    = block_reduce((tid < NBLK) ? ws->dotParts[tid] : 0.0, s16);
    const double errA  = block_reduce((tid < NBLK) ? ws->errAParts[tid]: 0.0, s16);
    const double errB  = block_reduce((tid < NBLK) ? ws->errBParts[tid]: 0.0, s16);
    const double W0 = D_MASS / k0sum;
    const double Wn = D_MASS / sd;
    const double err2 = W0 * W0 * s2tot - 2.0 * W0 * Wn * errA + Wn * Wn * errB;

    if (sqrt(err2) <= D_TOL) {
        // ---- fast path: converged at iter 0; write output, no sync ----
        const int i = r0 + rloc;
        const double unw = Wn * (double)ws->U[i];
        const float4* c4  = (const float4*)(C + (size_t)i * N);
        const float4* vn4 = (const float4*)ws->V;
        float4* k4p = (float4*)(K + (size_t)i * N);
        #pragma unroll 4
        for (int j4 = cgrp; j4 < N / 4; j4 += 128) {
            float4 c = c4[j4], vn = vn4[j4];
            float4 kn;
            kn.x = (float)(unw * (double)expf(-10.0f * c.x) * (double)vn.x);
            kn.y = (float)(unw * (double)expf(-10.0f * c.y) * (double)vn.y);
            kn.z = (float)(unw * (double)expf(-10.0f * c.z) * (double)vn.z);
            kn.w = (float)(unw * (double)expf(-10.0f * c.w) * (double)vn.w);
            k4p[j4] = kn;
        }
        return;
    }

    // ---- fallback: load iter-0 state, rebuild band, iterate 1..49 ----
    if (tid < RPB) {
        sU[tid] = (double)ws->U[r0 + tid];
        sRowPrev[tid] = (double)ws->row_prev[r0 + tid];
        sVown[tid] = (double)ws->V[r0 + tid];
        sColPrev[tid] = (double)ws->col_prev[r0 + tid];
        sAn[tid] = (double)a[r0 + tid] / ws->a_sum;
        sBn[tid] = (double)b[r0 + tid] / ws->b_sum;
        sUp[tid] = 1.0;
    }
    {
        const int i = r0 + rloc;
        const float4* c4 = (const float4*)(C + (size_t)i * N);
        #pragma unroll 4
        for (int j4 = cgrp; j4 < N / 4; j4 += 128) {
            float4 c = c4[j4];
            half4_t h;
            h[0] = (_Float16)expf(-10.0f * c.x);
            h[1] = (_Float16)expf(-10.0f * c.y);
            h[2] = (_Float16)expf(-10.0f * c.z);
            h[3] = (_Float16)expf(-10.0f * c.w);
            *(half4_t*)&band[rloc][4 * j4] = h;
        }
    }
    __syncthreads();

    double W = 0.0, Wp = 0.0;
    bool done = false;

    for (int cpt = 1; cpt < NITER && !done; ++cpt) {
        const bool erriter = (cpt % 10) == 0;

        if (cpt > 1) wait_cnt(&ws->cntV, (unsigned)(NBLK * (cpt - 1)));
        W = D_MASS / block_reduce((tid < NBLK) ? ws->dotParts[tid] : 0.0, s16);
        if (erriter) {
            Wp = W;
            if (tid < RPB) sUp[tid] = sU[tid];
        }
        __syncthreads();

        // A1: row sums (band x V) + row scaling
        {
            const float4* v4 = (const float4*)ws->V;
            double s = 0.0;
            #pragma unroll 4
            for (int j4 = cgrp; j4 < N / 4; j4 += 128) {
                half4_t h = *(const half4_t*)&band[rloc][4 * j4];
                float4 vv = v4[j4];
                s += (double)((float)h[0] * vv.x) + (double)((float)h[1] * vv.y)
                   + (double)((float)h[2] * vv.z) + (double)((float)h[3] * vv.w);
            }
            for (int off = 32; off; off >>= 1) s += __shfl_xor(s, off, 64);
            __syncthreads();
            if (lane == 0) s16[tid >> 6] = s;
            __syncthreads();
            if (tid < RPB) {
                const double Uq = sU[tid] / sRowPrev[tid];
                double r = sAn[tid] / (Uq * W * (s16[2 * tid] + s16[2 * tid + 1]));
                if (r > 1.0) r = 1.0;
                sU[tid] = Uq * r; sRowPrev[tid] = r;
            }
        }
        __syncthreads();

        // A2: column partials -> [col][srcblk]
        {
            double ub[RPB];
            #pragma unroll
            for (int r = 0; r < RPB; ++r) ub[r] = sU[r];
            const int j0 = 2 * tid;
            double ax = 0.0, ay = 0.0;
            #pragma unroll
            for (int r = 0; r < RPB; ++r) {
                half2_t hv = *(const half2_t*)&band[r][j0];
                ax += (double)(float)hv[0] * ub[r];
                ay += (double)(float)hv[1] * ub[r];
            }
            ws->partialT[(size_t)j0 * NBLK + bid]       = (float)ax;
            ws->partialT[(size_t)(j0 + 1) * NBLK + bid] = (float)ay;
        }
        arrive(&ws->cntP);
        wait_cnt(&ws->cntP, (unsigned)(NBLK * cpt));

        // B: own 8 columns (coalesced), col scaling, V, dot partial
        {
            const int jj = tid >> 7, p = tid & 127;
            const int j = r0 + jj;
            double t = (double)ws->partialT[(size_t)j * NBLK + p]
                     + (double)ws->partialT[(size_t)j * NBLK + 128 + p];
            for (int off = 32; off; off >>= 1) t += __shfl_xor(t, off, 64);
            __syncthreads();
            if (lane == 0) s16[tid >> 6] = t;
            __syncthreads();
            if (tid < RPB) {
                const double Tj = s16[2 * tid] + s16[2 * tid + 1];
                const double Vq = sVown[tid] / sColPrev[tid];
                double cf = sBn[tid] / (Vq * W * Tj);
                if (cf > 1.0) cf = 1.0;
                if (erriter) ws->Vp[r0 + tid] = (float)sVown[tid];
                const double Vn = Vq * cf;
                sVown[tid] = Vn; sColPrev[tid] = cf;
                ws->V[r0 + tid] = (float)Vn;
                sDot[tid] = Tj * Vn;
            }
            __syncthreads();
            if (tid == 0) {
                double d = 0.0;
                #pragma unroll
                for (int q = 0; q < RPB; ++q) d += sDot[q];
                ws->dotParts[bid] = d;
            }
        }
        arrive(&ws->cntV);

        // err check + speculative output (every 10 iters)
        if (erriter) {
            wait_cnt(&ws->cntV, (unsigned)(NBLK * cpt));
            const double sdl = block_reduce((tid < NBLK) ? ws->dotParts[tid] : 0.0, s16);
            const double Wc = D_MASS / sdl;
            const int i = r0 + rloc;
            const double upw = sUp[rloc] * Wp;
            const double unw = sU[rloc] * Wc;
            const float4* vp4 = (const float4*)ws->Vp;
            const float4* vn4 = (const float4*)ws->V;
            float4* k4p = (float4*)(K + (size_t)i * N);
            double e2 = 0.0;
            #pragma unroll 4
            for (int j4 = cgrp; j4 < N / 4; j4 += 128) {
                half4_t h = *(const half4_t*)&band[rloc][4 * j4];
                float4 vp = vp4[j4], vn = vn4[j4];
                double d;
                d = (double)(float)h[0] * (upw * (double)vp.x - unw * (double)vn.x); e2 += d * d;
                d = (double)(float)h[1] * (upw * (double)vp.y - unw * (double)vn.y); e2 += d * d;
                d = (double)(float)h[2] * (upw * (double)vp.z - unw * (double)vn.z); e2 += d * d;
                d = (double)(float)h[3] * (upw * (double)vp.w - unw * (double)vn.w); e2 += d * d;
            }
            const double be = block_reduce(e2, s16);
            if (tid == 0) ws->errParts[bid] = be;
            arrive(&ws->cntE);
            // speculative output overlaps flag propagation
            #pragma unroll 4
            for (int j4 = cgrp; j4 < N / 4; j4 += 128) {
                half4_t h = *(const half4_t*)&band[rloc][4 * j4];
                float4 vn = vn4[j4];
                float4 kn;
                kn.x = (float)(unw * (double)(float)h[0] * (double)vn.x);
                kn.y = (float)(unw * (double)(float)h[1] * (double)vn.y);
                kn.z = (float)(unw * (double)(float)h[2] * (double)vn.z);
                kn.w = (float)(unw * (double)(float)h[3] * (double)vn.w);
                k4p[j4] = kn;
            }
            wait_cnt(&ws->cntE, (unsigned)(NBLK * (cpt / 10)));
            const double te = block_reduce((tid < NBLK) ? ws->errParts[tid] : 0.0, s16);
            done = (sqrt(te) <= D_TOL);      // bitwise-identical everywhere
        }
    }

    if (!done) {   // ran out of iterations: final output from current state
        wait_cnt(&ws->cntV, (unsigned)(NBLK * (NITER - 1)));
        const double sdl = block_reduce((tid < NBLK) ? ws->dotParts[tid] : 0.0, s16);
        const double Wf = D_MASS / sdl;
        const int i = r0 + rloc;
        const double uf = sU[rloc] * Wf;
        const float4* vn4 = (const float4*)ws->V;
        float4* k4p = (float4*)(K + (size_t)i * N);
        #pragma unroll 4
        for (int j4 = cgrp; j4 < N / 4; j4 += 128) {
            half4_t h = *(const half4_t*)&band[rloc][4 * j4];
            float4 vv = vn4[j4];
            float4 o;
            o.x = (float)(uf * (double)(float)h[0] * (double)vv.x);
            o.y = (float)(uf * (double)(float)h[1] * (double)vv.y);
            o.z = (float)(uf * (double)(float)h[2] * (double)vv.z);
            o.w = (float)(uf * (double)(float)h[3] * (double)vv.w);
            k4p[j4] = o;
        }
    }
}

extern "C" void kernel_launch(void* const* d_in, const int* in_sizes, int n_in,
                              void* d_out, int out_size, void* d_ws, size_t ws_size,
                              hipStream_t stream) {
    const float* C = (const float*)d_in[0];
    const float* a = (const float*)d_in[1];
    const float* b = (const float*)d_in[2];
    float* K = (float*)d_out;
    Ws*    w = (Ws*)d_ws;

    k1_sums<<<NBLK, NTHR, 0, stream>>>(C, a, b, w);
    k2_rowscale_colpart<<<NBLK, NTHR, 0, stream>>>(C, a, w);
    k3_colscale<<<NBLK, 256, 0, stream>>>(b, w);
    void* args[5] = { (void*)&C, (void*)&a, (void*)&b, (void*)&K, (void*)&w };
    (void)hipLaunchCooperativeKernel((const void*)k45_out_iters, dim3(NBLK), dim3(NTHR),
                                     args, 0, stream);
}